// Round 1
// baseline (126.106 us; speedup 1.0000x reference)
//
#include <hip/hip_runtime.h>
#include <hip/hip_bf16.h>

#define B_   16
#define CIN  256
#define COUT 256
#define HH   64
#define WW   64
#define WDIM 512
#define OH   128
#define OW   128

#define LDK 264   // padded K stride in LDS (bf16 units): 256+8
#define TPX 192   // 3 y-rows * 64 cols per tile
#define PXP 196   // padded pixel stride for ylds
#define MCH 32    // channels per m-chunk

typedef __attribute__((ext_vector_type(8))) short short8;
typedef __attribute__((ext_vector_type(4))) float f32x4;

__device__ __forceinline__ unsigned short f2bf(float f) {
    __hip_bfloat16 h = __float2bfloat16(f);
    return *reinterpret_cast<unsigned short*>(&h);
}

// ws layout (floats): [0..16) per-batch styles sumsq partials; [64..4160) styles
// byte 32768+: wb bf16 [16][256][256]  (2 MB)

__global__ __launch_bounds__(256) void k_styles(const float* __restrict__ w,
                                                const float* __restrict__ aw,
                                                const float* __restrict__ ab,
                                                float* __restrict__ ws) {
    int b = blockIdx.x, i = threadIdx.x;
    const float4* wr = (const float4*)(w + b * WDIM);
    const float4* ar = (const float4*)(aw + (size_t)i * WDIM);
    float acc = 0.f;
    #pragma unroll 4
    for (int k = 0; k < WDIM / 4; ++k) {
        float4 wv = wr[k], av = ar[k];
        acc += wv.x * av.x + wv.y * av.y + wv.z * av.z + wv.w * av.w;
    }
    const float wg = 0.04419417382415922f; // 1/sqrt(512)
    float st = acc * wg + ab[i];
    ws[64 + b * CIN + i] = st;
    __shared__ float sred[256];
    sred[i] = st * st;
    __syncthreads();
    for (int s = 128; s > 0; s >>= 1) {
        if (i < s) sred[i] += sred[i + s];
        __syncthreads();
    }
    if (i == 0) ws[b] = sred[0];
}

__global__ __launch_bounds__(64) void k_wb(const float* __restrict__ weight,
                                           const float* __restrict__ ws,
                                           unsigned short* __restrict__ wb) {
    int o = blockIdx.x, b = blockIdx.y, l = threadIdx.x;
    // global styles rms
    float tot = 0.f;
    #pragma unroll
    for (int j = 0; j < B_; ++j) tot += ws[j];
    float srs = rsqrtf(tot / (float)(B_ * CIN));
    // per-o weight rms
    float4 wk = *(const float4*)(weight + (size_t)o * CIN + l * 4);
    float ss = wk.x * wk.x + wk.y * wk.y + wk.z * wk.z + wk.w * wk.w;
    #pragma unroll
    for (int off = 32; off; off >>= 1) ss += __shfl_xor(ss, off);
    float wkn = rsqrtf(ss / (float)CIN);
    float4 st = *(const float4*)(ws + 64 + b * CIN + l * 4);
    float4 t;
    t.x = wk.x * wkn * st.x * srs;
    t.y = wk.y * wkn * st.y * srs;
    t.z = wk.z * wkn * st.z * srs;
    t.w = wk.w * wkn * st.w * srs;
    float s2 = t.x * t.x + t.y * t.y + t.z * t.z + t.w * t.w;
    #pragma unroll
    for (int off = 32; off; off >>= 1) s2 += __shfl_xor(s2, off);
    float dcoef = rsqrtf(s2 + 1e-8f);
    ushort4 pk;
    pk.x = f2bf(t.x * dcoef);
    pk.y = f2bf(t.y * dcoef);
    pk.z = f2bf(t.z * dcoef);
    pk.w = f2bf(t.w * dcoef);
    *(ushort4*)(wb + ((size_t)b * COUT + o) * CIN + l * 4) = pk;
}

__global__ __launch_bounds__(512) void k_main(const float* __restrict__ x,
                                              const float* __restrict__ bias,
                                              const unsigned short* __restrict__ wb,
                                              float* __restrict__ out) {
    __shared__ __align__(16) unsigned short xt[TPX * LDK]; // 101376 B
    __shared__ __align__(16) float ylds[MCH * PXP];        // 25088 B
    const int t = blockIdx.x;   // row tile 0..31
    const int b = blockIdx.y;
    const int tid = threadIdx.x;
    const int lane = tid & 63, wv = tid >> 6;
    const int rowbase = 2 * t - 1;

    // ---- stage x tile (3 rows, row-clamped) as bf16, [px][K] K-contiguous ----
    {
        const int g = tid & 15;   // pixel group (12 px)
        const int k8 = tid >> 4;  // 0..31 (8 channels each)
        const float* xb = x + (size_t)b * CIN * HH * WW;
        #pragma unroll
        for (int i = 0; i < 3; ++i) {
            int p = g * 12 + i * 4;
            int lr = p >> 6, c = p & 63;
            int grow = rowbase + lr;
            grow = min(max(grow, 0), HH - 1);
            int gp = grow * WW + c;
            float4 v[8];
            #pragma unroll
            for (int kk = 0; kk < 8; ++kk)
                v[kk] = *(const float4*)(xb + (size_t)(k8 * 8 + kk) * (HH * WW) + gp);
            #pragma unroll
            for (int j = 0; j < 4; ++j) {
                union { short8 s; unsigned short u[8]; } pk;
                #pragma unroll
                for (int kk = 0; kk < 8; ++kk) {
                    float f = (j == 0) ? v[kk].x : (j == 1) ? v[kk].y : (j == 2) ? v[kk].z : v[kk].w;
                    pk.u[kk] = f2bf(f);
                }
                *reinterpret_cast<short8*>(&xt[(p + j) * LDK + k8 * 8]) = pk.s;
            }
        }
    }
    __syncthreads();

    const int wm = wv & 1, wn = wv >> 1;
    const int n0 = wn * 48;
    const int hi = lane >> 4, lo = lane & 15;
    const unsigned short* wbp = wb + (size_t)b * COUT * CIN;

    const int ostart = (t == 0) ? 0 : (4 * t - 1);
    const int oend = (t == 31) ? 128 : (4 * t + 3);
    const int nrows = oend - ostart;
    const int iters = 2 * nrows;

    for (int mc = 0; mc < COUT / MCH; ++mc) {
        const int m0 = mc * MCH + wm * 16;
        f32x4 acc0 = {0.f, 0.f, 0.f, 0.f};
        f32x4 acc1 = {0.f, 0.f, 0.f, 0.f};
        f32x4 acc2 = {0.f, 0.f, 0.f, 0.f};
        #pragma unroll
        for (int ks = 0; ks < 8; ++ks) {
            const int k0 = ks * 32;
            short8 a = *(const short8*)(wbp + (size_t)(m0 + lo) * CIN + k0 + hi * 8);
            short8 b0 = *(const short8*)&xt[(n0 + lo) * LDK + k0 + hi * 8];
            short8 b1 = *(const short8*)&xt[(n0 + 16 + lo) * LDK + k0 + hi * 8];
            short8 b2 = *(const short8*)&xt[(n0 + 32 + lo) * LDK + k0 + hi * 8];
            acc0 = __builtin_amdgcn_mfma_f32_16x16x32_bf16(a, b0, acc0, 0, 0, 0);
            acc1 = __builtin_amdgcn_mfma_f32_16x16x32_bf16(a, b1, acc1, 0, 0, 0);
            acc2 = __builtin_amdgcn_mfma_f32_16x16x32_bf16(a, b2, acc2, 0, 0, 0);
        }
        // write y chunk (+bias) to LDS: D layout col=lane&15, row=(lane>>4)*4+j
        const int mloc = wm * 16 + hi * 4;
        #pragma unroll
        for (int j = 0; j < 4; ++j) {
            float bs = bias[mc * MCH + mloc + j];
            ylds[(mloc + j) * PXP + n0 + lo]      = acc0[j] + bs;
            ylds[(mloc + j) * PXP + n0 + 16 + lo] = acc1[j] + bs;
            ylds[(mloc + j) * PXP + n0 + 32 + lo] = acc2[j] + bs;
        }
        __syncthreads();

        // fused bilinear 2x upsample epilogue for this chunk
        for (int it = 0; it < iters; ++it) {
            int f = it * 512 + tid;
            int q = f & 31;          // output col quad
            int rest = f >> 5;
            int ch = rest & 31;      // channel within chunk
            int ori = rest >> 5;     // 0..nrows-1
            int o = ostart + ori;
            int yr0 = (o - 1) >> 1;
            int lr0 = min(max(yr0, 0), HH - 1) - rowbase;
            int lr1 = min(max(yr0 + 1, 0), HH - 1) - rowbase;
            float wr0 = (o & 1) ? 0.75f : 0.25f;
            float wr1 = 1.f - wr0;
            int cA = max(2 * q - 1, 0), cB = 2 * q;
            int cC = min(2 * q + 1, WW - 1), cD = min(2 * q + 2, WW - 1);
            const float* Y = &ylds[ch * PXP];
            float rA = wr0 * Y[lr0 * 64 + cA] + wr1 * Y[lr1 * 64 + cA];
            float rB = wr0 * Y[lr0 * 64 + cB] + wr1 * Y[lr1 * 64 + cB];
            float rC = wr0 * Y[lr0 * 64 + cC] + wr1 * Y[lr1 * 64 + cC];
            float rD = wr0 * Y[lr0 * 64 + cD] + wr1 * Y[lr1 * 64 + cD];
            float4 ov;
            ov.x = 0.25f * rA + 0.75f * rB;
            ov.y = 0.75f * rB + 0.25f * rC;
            ov.z = 0.25f * rB + 0.75f * rC;
            ov.w = 0.75f * rC + 0.25f * rD;
            float* op = out + ((((size_t)b * COUT + mc * MCH + ch) * OH + o) * OW + q * 4);
            *(float4*)op = ov;
        }
        __syncthreads();
    }
}

extern "C" void kernel_launch(void* const* d_in, const int* in_sizes, int n_in,
                              void* d_out, int out_size, void* d_ws, size_t ws_size,
                              hipStream_t stream) {
    (void)in_sizes; (void)n_in; (void)out_size; (void)ws_size;
    const float* x      = (const float*)d_in[0];
    const float* w      = (const float*)d_in[1];
    const float* aw     = (const float*)d_in[2];
    const float* ab     = (const float*)d_in[3];
    const float* weight = (const float*)d_in[4];
    const float* bias   = (const float*)d_in[5];
    float* out = (float*)d_out;
    float* wsf = (float*)d_ws;
    unsigned short* wb = (unsigned short*)((char*)d_ws + 32768);

    hipLaunchKernelGGL(k_styles, dim3(16), dim3(256), 0, stream, w, aw, ab, wsf);
    hipLaunchKernelGGL(k_wb, dim3(COUT, B_), dim3(64), 0, stream, weight, wsf, wb);
    hipLaunchKernelGGL(k_main, dim3(32, B_), dim3(512), 0, stream, x, bias, wb, out);
}

// Round 2
// 122.930 us; speedup vs baseline: 1.0258x; 1.0258x over previous
//
#include <hip/hip_runtime.h>
#include <hip/hip_bf16.h>

#define B_   16
#define CIN  256
#define COUT 256
#define HH   64
#define WW   64
#define WDIM 512
#define OH   128
#define OW   128

#define PX   128  // 2 input rows * 64 cols per tile
#define LDK  264  // padded K stride in LDS (bf16 units): 256+8
#define YLP  136  // padded pixel stride for ylds (bf16 units): 128+8
#define MCH  32   // channels per m-chunk

typedef __attribute__((ext_vector_type(8))) short short8;
typedef __attribute__((ext_vector_type(4))) float f32x4;

__device__ __forceinline__ unsigned short f2bf(float f) {
    __hip_bfloat16 h = __float2bfloat16(f);
    return *reinterpret_cast<unsigned short*>(&h);
}
__device__ __forceinline__ float bf2f(unsigned short u) {
    unsigned int t = ((unsigned int)u) << 16;
    return *reinterpret_cast<float*>(&t);
}

// ws layout (floats): [0..16) per-batch styles sumsq partials; [64..4160) styles
// byte 32768+: wb bf16 [16][256][256]  (2 MB)

__global__ __launch_bounds__(256) void k_styles(const float* __restrict__ w,
                                                const float* __restrict__ aw,
                                                const float* __restrict__ ab,
                                                float* __restrict__ ws) {
    int b = blockIdx.x, i = threadIdx.x;
    const float4* wr = (const float4*)(w + b * WDIM);
    const float4* ar = (const float4*)(aw + (size_t)i * WDIM);
    float acc = 0.f;
    #pragma unroll 4
    for (int k = 0; k < WDIM / 4; ++k) {
        float4 wv = wr[k], av = ar[k];
        acc += wv.x * av.x + wv.y * av.y + wv.z * av.z + wv.w * av.w;
    }
    const float wg = 0.04419417382415922f; // 1/sqrt(512)
    float st = acc * wg + ab[i];
    ws[64 + b * CIN + i] = st;
    __shared__ float sred[256];
    sred[i] = st * st;
    __syncthreads();
    for (int s = 128; s > 0; s >>= 1) {
        if (i < s) sred[i] += sred[i + s];
        __syncthreads();
    }
    if (i == 0) ws[b] = sred[0];
}

__global__ __launch_bounds__(64) void k_wb(const float* __restrict__ weight,
                                           const float* __restrict__ ws,
                                           unsigned short* __restrict__ wb) {
    int o = blockIdx.x, b = blockIdx.y, l = threadIdx.x;
    float tot = 0.f;
    #pragma unroll
    for (int j = 0; j < B_; ++j) tot += ws[j];
    float srs = rsqrtf(tot / (float)(B_ * CIN));
    float4 wk = *(const float4*)(weight + (size_t)o * CIN + l * 4);
    float ss = wk.x * wk.x + wk.y * wk.y + wk.z * wk.z + wk.w * wk.w;
    #pragma unroll
    for (int off = 32; off; off >>= 1) ss += __shfl_xor(ss, off);
    float wkn = rsqrtf(ss / (float)CIN);
    float4 st = *(const float4*)(ws + 64 + b * CIN + l * 4);
    float4 t;
    t.x = wk.x * wkn * st.x * srs;
    t.y = wk.y * wkn * st.y * srs;
    t.z = wk.z * wkn * st.z * srs;
    t.w = wk.w * wkn * st.w * srs;
    float s2 = t.x * t.x + t.y * t.y + t.z * t.z + t.w * t.w;
    #pragma unroll
    for (int off = 32; off; off >>= 1) s2 += __shfl_xor(s2, off);
    float dcoef = rsqrtf(s2 + 1e-8f);
    ushort4 pk;
    pk.x = f2bf(t.x * dcoef);
    pk.y = f2bf(t.y * dcoef);
    pk.z = f2bf(t.z * dcoef);
    pk.w = f2bf(t.w * dcoef);
    *(ushort4*)(wb + ((size_t)b * COUT + o) * CIN + l * 4) = pk;
}

// Block r stages input rows {r, min(r+1,63)} x 64 cols x 256 ch (bf16 in LDS),
// produces out rows {2r+1, 2r+2} (block 0 adds row 0; block 63 emits only 127).
__global__ __launch_bounds__(512, 4) void k_main(const float* __restrict__ x,
                                                 const float* __restrict__ bias,
                                                 const unsigned short* __restrict__ wb,
                                                 float* __restrict__ out) {
    __shared__ __align__(16) unsigned short xt[PX * LDK];    // 67584 B
    __shared__ __align__(16) unsigned short ylds[MCH * YLP]; // 8704 B
    const int r = blockIdx.x;   // 0..63
    const int b = blockIdx.y;
    const int tid = threadIdx.x;
    const int lane = tid & 63;

    // ---- stage: 32 lanes read 512B contiguous per instr, bf16 [px][K] ----
    {
        const int g = tid & 31;        // px quad: px = g*4..g*4+3
        const int kk = tid >> 5;       // 0..15 -> channels kk*16..kk*16+15
        const int row = g >> 4;
        const int col4 = (g & 15) * 4;
        const int grow = min(r + row, HH - 1);
        const float* xp = x + (size_t)b * CIN * HH * WW + grow * WW + col4;
        const int px0 = g * 4;
        #pragma unroll
        for (int grp = 0; grp < 2; ++grp) {
            float4 v[8];
            #pragma unroll
            for (int c = 0; c < 8; ++c)
                v[c] = *(const float4*)(xp + (size_t)(kk * 16 + grp * 8 + c) * (HH * WW));
            #pragma unroll
            for (int j = 0; j < 4; ++j) {
                union { short8 s; unsigned short u[8]; } pk;
                #pragma unroll
                for (int c = 0; c < 8; ++c) {
                    float f = (j == 0) ? v[c].x : (j == 1) ? v[c].y : (j == 2) ? v[c].z : v[c].w;
                    pk.u[c] = f2bf(f);
                }
                *reinterpret_cast<short8*>(&xt[(px0 + j) * LDK + kk * 16 + grp * 8]) = pk.s;
            }
        }
    }
    __syncthreads();

    const int wv = tid >> 6;
    const int wm = wv & 1, wn = wv >> 1;   // 2 m-frags x 4 n-groups
    const int n0 = wn * 32;
    const int hi = lane >> 4, lo = lane & 15;
    const unsigned short* wbp = wb + (size_t)b * COUT * CIN;

    const int ostart = (r == 0) ? 0 : (2 * r + 1);
    const int oend = (r == HH - 1) ? OH : (2 * r + 3);
    const int nrows = oend - ostart;
    const int iters = 2 * nrows;

    for (int mc = 0; mc < COUT / MCH; ++mc) {
        const int m0 = mc * MCH + wm * 16;
        f32x4 acc0 = {0.f, 0.f, 0.f, 0.f};
        f32x4 acc1 = {0.f, 0.f, 0.f, 0.f};
        #pragma unroll
        for (int ks = 0; ks < 8; ++ks) {
            const int k0 = ks * 32;
            short8 a  = *(const short8*)(wbp + (size_t)(m0 + lo) * CIN + k0 + hi * 8);
            short8 b0 = *(const short8*)&xt[(n0 + lo) * LDK + k0 + hi * 8];
            short8 b1 = *(const short8*)&xt[(n0 + 16 + lo) * LDK + k0 + hi * 8];
            acc0 = __builtin_amdgcn_mfma_f32_16x16x32_bf16(a, b0, acc0, 0, 0, 0);
            acc1 = __builtin_amdgcn_mfma_f32_16x16x32_bf16(a, b1, acc1, 0, 0, 0);
        }
        // D layout: col(n)=lane&15, row(m)=(lane>>4)*4+j
        const int mloc = wm * 16 + hi * 4;
        #pragma unroll
        for (int j = 0; j < 4; ++j) {
            float bs = bias[mc * MCH + mloc + j];
            ylds[(mloc + j) * YLP + n0 + lo]      = f2bf(acc0[j] + bs);
            ylds[(mloc + j) * YLP + n0 + 16 + lo] = f2bf(acc1[j] + bs);
        }
        __syncthreads();

        // fused bilinear 2x upsample for this 32-channel chunk
        for (int it = 0; it < iters; ++it) {
            int f = it * 512 + tid;
            int q = f & 31;          // output col quad
            int ch = (f >> 5) & 31;  // channel within chunk
            int ori = f >> 10;       // 0..nrows-1
            int o = ostart + ori;
            int yr0 = (o - 1) >> 1;
            int lr0 = min(max(yr0, 0), HH - 1) - r;      // 0
            int lr1 = min(yr0 + 1, HH - 1) - r;          // 0 or 1
            float wr0 = (o & 1) ? 0.75f : 0.25f;
            float wr1 = 1.f - wr0;
            int cA = max(2 * q - 1, 0), cB = 2 * q;
            int cC = min(2 * q + 1, WW - 1), cD = min(2 * q + 2, WW - 1);
            const unsigned short* Y = &ylds[ch * YLP];
            float rA = wr0 * bf2f(Y[lr0 * 64 + cA]) + wr1 * bf2f(Y[lr1 * 64 + cA]);
            float rB = wr0 * bf2f(Y[lr0 * 64 + cB]) + wr1 * bf2f(Y[lr1 * 64 + cB]);
            float rC = wr0 * bf2f(Y[lr0 * 64 + cC]) + wr1 * bf2f(Y[lr1 * 64 + cC]);
            float rD = wr0 * bf2f(Y[lr0 * 64 + cD]) + wr1 * bf2f(Y[lr1 * 64 + cD]);
            float4 ov;
            ov.x = 0.25f * rA + 0.75f * rB;
            ov.y = 0.75f * rB + 0.25f * rC;
            ov.z = 0.25f * rB + 0.75f * rC;
            ov.w = 0.75f * rC + 0.25f * rD;
            float* op = out + ((((size_t)b * COUT + mc * MCH + ch) * OH + o) * OW + q * 4);
            *(float4*)op = ov;
        }
        __syncthreads();
    }
}

extern "C" void kernel_launch(void* const* d_in, const int* in_sizes, int n_in,
                              void* d_out, int out_size, void* d_ws, size_t ws_size,
                              hipStream_t stream) {
    (void)in_sizes; (void)n_in; (void)out_size; (void)ws_size;
    const float* x      = (const float*)d_in[0];
    const float* w      = (const float*)d_in[1];
    const float* aw     = (const float*)d_in[2];
    const float* ab     = (const float*)d_in[3];
    const float* weight = (const float*)d_in[4];
    const float* bias   = (const float*)d_in[5];
    float* out = (float*)d_out;
    float* wsf = (float*)d_ws;
    unsigned short* wb = (unsigned short*)((char*)d_ws + 32768);

    hipLaunchKernelGGL(k_styles, dim3(16), dim3(256), 0, stream, w, aw, ab, wsf);
    hipLaunchKernelGGL(k_wb, dim3(COUT, B_), dim3(64), 0, stream, weight, wsf, wb);
    hipLaunchKernelGGL(k_main, dim3(HH, B_), dim3(512), 0, stream, x, bias, wb, out);
}